// Round 2
// baseline (811.485 us; speedup 1.0000x reference)
//
#include <hip/hip_runtime.h>

#define VOCAB 10000
#define HIDDEN 256
#define BATCH 32
#define SEQ 256
#define M_ROWS 8192           // SEQ * BATCH
#define NPAD 10112            // 79 * 128
#define NTILES 79
#define MTILES 64             // 8192 / 128
#define LOGITS_ELEMS 81920000LL

typedef __attribute__((ext_vector_type(8))) short short8;
typedef __attribute__((ext_vector_type(4))) float f32x4;

static __device__ __forceinline__ unsigned short f32_to_bf16(float f) {
    unsigned u = __float_as_uint(f);
    u += 0x7fffu + ((u >> 16) & 1u);   // round-to-nearest-even
    return (unsigned short)(u >> 16);
}

// ---------------------------------------------------------------------------
// Kernel 1: W_ihT[v][h] = W_ih[h][v]  (10000 x 256 fp32) — one block per v
// ---------------------------------------------------------------------------
__global__ __launch_bounds__(256) void transpose_wih(const float* __restrict__ W_ih,
                                                     float* __restrict__ W_ihT) {
    const int v = blockIdx.x;        // 0..9999
    const int h = threadIdx.x;       // 0..255
    W_ihT[(long)v * HIDDEN + h] = W_ih[(long)h * VOCAB + v];
}

// ---------------------------------------------------------------------------
// Kernel 2: Wb = bf16(W_out) padded with zero rows to NPAD — one block per row
// ---------------------------------------------------------------------------
__global__ __launch_bounds__(256) void prep_wout(const float* __restrict__ W_out,
                                                 unsigned short* __restrict__ Wb) {
    const int n = blockIdx.x;        // 0..10111
    const int k = threadIdx.x;
    float v = (n < VOCAB) ? W_out[(long)n * HIDDEN + k] : 0.f;
    Wb[(long)n * HIDDEN + k] = f32_to_bf16(v);
}

// ---------------------------------------------------------------------------
// Kernel 3: RNN scan. One block per batch row; W_hh resident in VGPRs.
// Thread t: q = t>>6 == wave id (k-chunk of 64), jj = t&63; rows jj+64r.
// ---------------------------------------------------------------------------
__global__ __launch_bounds__(256, 1) void scan_kernel(
        const int*   __restrict__ inputs,   // (32, 256)
        const float* __restrict__ state,    // (1, 32, 256)
        const float* __restrict__ W_hh,     // (256, 256)
        const float* __restrict__ b_ih,
        const float* __restrict__ b_hh,
        const float* __restrict__ W_ihT,    // (10000, 256)
        unsigned short* __restrict__ Ybf,   // (8192, 256) bf16
        float* __restrict__ hout)           // (32, 256)
{
    __shared__ float hbuf[HIDDEN];
    __shared__ float psum[4 * HIDDEN];

    const int b  = blockIdx.x;
    const int t  = threadIdx.x;
    const int q  = t >> 6;
    const int jj = t & 63;

    // Load my 4x64 slice of W_hh into registers (one-time)
    float w[4][64];
#pragma unroll
    for (int r = 0; r < 4; ++r) {
        const float* src = W_hh + (jj + 64 * r) * HIDDEN + 64 * q;
#pragma unroll
        for (int k4 = 0; k4 < 16; ++k4) {
            const float4 v = *(const float4*)(src + 4 * k4);
            w[r][4 * k4 + 0] = v.x;
            w[r][4 * k4 + 1] = v.y;
            w[r][4 * k4 + 2] = v.z;
            w[r][4 * k4 + 3] = v.w;
        }
    }

    const float biasv = b_ih[t] + b_hh[t];
    hbuf[t] = state[b * HIDDEN + t];
    int tok0 = inputs[b * SEQ + 0];
    float xcur = W_ihT[(long)tok0 * HIDDEN + t];
    __syncthreads();

    for (int step = 0; step < SEQ; ++step) {
        // prefetch next step's embedding column (coalesced row of W_ihT)
        float xnext = 0.f;
        if (step + 1 < SEQ) {
            int tokn = inputs[b * SEQ + step + 1];
            xnext = W_ihT[(long)tokn * HIDDEN + t];
        }

        // partial dot-products: rows jj+64r over k in [64q, 64q+64)
        float acc[4] = {0.f, 0.f, 0.f, 0.f};
#pragma unroll
        for (int k4 = 0; k4 < 16; ++k4) {
            const float4 hv = *(const float4*)&hbuf[64 * q + 4 * k4];  // broadcast
#pragma unroll
            for (int r = 0; r < 4; ++r) {
                acc[r] = fmaf(w[r][4 * k4 + 0], hv.x, acc[r]);
                acc[r] = fmaf(w[r][4 * k4 + 1], hv.y, acc[r]);
                acc[r] = fmaf(w[r][4 * k4 + 2], hv.z, acc[r]);
                acc[r] = fmaf(w[r][4 * k4 + 3], hv.w, acc[r]);
            }
        }
#pragma unroll
        for (int r = 0; r < 4; ++r)
            psum[q * HIDDEN + jj + 64 * r] = acc[r];   // stride-1 per wave
        __syncthreads();

        // reduce 4 chunk-partials for row j = t, apply x + biases, tanh
        float s = psum[t] + psum[HIDDEN + t] + psum[2 * HIDDEN + t] + psum[3 * HIDDEN + t];
        float hnew = tanhf(s + xcur + biasv);
        hbuf[t] = hnew;
        Ybf[((long)step * BATCH + b) * HIDDEN + t] = f32_to_bf16(hnew);
        xcur = xnext;
        __syncthreads();
    }

    hout[b * HIDDEN + t] = hbuf[t];
}

// ---------------------------------------------------------------------------
// Kernel 4: logits = Y(bf16) @ Wb^T + b_out.  m97-style 128x128 tile, BK=64,
// global_load_lds width-16 staging, 16x16x32 bf16 MFMA, 4x4 frags per wave.
// ---------------------------------------------------------------------------
__global__ __launch_bounds__(256) void gemm_kernel(
        const unsigned short* __restrict__ A,   // (8192, 256) bf16
        const unsigned short* __restrict__ B,   // (10112, 256) bf16
        const float* __restrict__ bias,         // (10000,)
        float* __restrict__ C)                  // (8192, 10000) f32
{
    __shared__ unsigned short lA[128 * 64];
    __shared__ unsigned short lB[128 * 64];

    const int t     = threadIdx.x;
    const int bid   = blockIdx.x;
    const int ntile = bid % NTILES;
    const int mtile = bid / NTILES;
    const long m0   = (long)mtile * 128;
    const long n0   = (long)ntile * 128;
    const int lane  = t & 63;
    const int wave  = t >> 6;
    const int wm    = (wave & 1) * 64;
    const int wn    = (wave >> 1) * 64;
    const int l15   = lane & 15;
    const int quad  = lane >> 4;

    const f32x4 zero = {0.f, 0.f, 0.f, 0.f};
    f32x4 acc[4][4];
#pragma unroll
    for (int i = 0; i < 4; ++i)
#pragma unroll
        for (int j = 0; j < 4; ++j)
            acc[i][j] = zero;

    for (int kb = 0; kb < 4; ++kb) {
        if (kb) __syncthreads();
        // stage A/B tiles: 128 rows x 64 bf16; 16 B per lane per issue;
        // LDS layout [row][k] (128 B rows) == contiguous in lane order
#pragma unroll
        for (int it = 0; it < 4; ++it) {
            const int c   = it * 256 + t;
            const int row = c >> 3;
            const int k8  = c & 7;
            const unsigned short* ga = A + (m0 + row) * HIDDEN + kb * 64 + k8 * 8;
            const unsigned short* gb = B + (n0 + row) * HIDDEN + kb * 64 + k8 * 8;
            __builtin_amdgcn_global_load_lds(
                (const __attribute__((address_space(1))) void*)ga,
                (__attribute__((address_space(3))) void*)(lA + c * 8), 16, 0, 0);
            __builtin_amdgcn_global_load_lds(
                (const __attribute__((address_space(1))) void*)gb,
                (__attribute__((address_space(3))) void*)(lB + c * 8), 16, 0, 0);
        }
        __syncthreads();

#pragma unroll
        for (int ki = 0; ki < 2; ++ki) {
            short8 af[4], bf[4];
#pragma unroll
            for (int i = 0; i < 4; ++i) {
                af[i] = *(const short8*)&lA[(wm + 16 * i + l15) * 64 + ki * 32 + quad * 8];
                bf[i] = *(const short8*)&lB[(wn + 16 * i + l15) * 64 + ki * 32 + quad * 8];
            }
#pragma unroll
            for (int i = 0; i < 4; ++i)
#pragma unroll
                for (int j = 0; j < 4; ++j)
                    acc[i][j] = __builtin_amdgcn_mfma_f32_16x16x32_bf16(
                        af[i], bf[j], acc[i][j], 0, 0, 0);
        }
    }

    // epilogue: C/D layout col = lane&15, row = quad*4 + reg
#pragma unroll
    for (int j = 0; j < 4; ++j) {
        const long col = n0 + wn + 16 * j + l15;
        if (col < VOCAB) {
            const float bv = bias[col];
#pragma unroll
            for (int i = 0; i < 4; ++i) {
                const long row = m0 + wm + 16 * i + quad * 4;
                float* Cp = C + row * VOCAB + col;
#pragma unroll
                for (int r = 0; r < 4; ++r)
                    Cp[(long)r * VOCAB] = acc[i][j][r] + bv;
            }
        }
    }
}

// ---------------------------------------------------------------------------
extern "C" void kernel_launch(void* const* d_in, const int* in_sizes, int n_in,
                              void* d_out, int out_size, void* d_ws, size_t ws_size,
                              hipStream_t stream) {
    const int*   inputs = (const int*)  d_in[0];
    const float* state  = (const float*)d_in[1];
    const float* W_ih   = (const float*)d_in[2];
    const float* b_ih   = (const float*)d_in[3];
    const float* W_hh   = (const float*)d_in[4];
    const float* b_hh   = (const float*)d_in[5];
    const float* W_out  = (const float*)d_in[6];
    const float* b_out  = (const float*)d_in[7];
    float* out = (float*)d_out;

    char* ws = (char*)d_ws;
    float*          W_ihT = (float*)ws;                        // 10,240,000 B
    unsigned short* Wb    = (unsigned short*)(ws + 10240000);  //  5,177,344 B
    unsigned short* Ybf   = (unsigned short*)(ws + 15417344);  //  4,194,304 B
                                                               // total 19.6 MB

    transpose_wih<<<VOCAB, 256, 0, stream>>>(W_ih, W_ihT);
    prep_wout<<<NPAD, 256, 0, stream>>>(W_out, Wb);
    scan_kernel<<<BATCH, 256, 0, stream>>>(inputs, state, W_hh, b_ih, b_hh,
                                           W_ihT, Ybf, out + LOGITS_ELEMS);
    gemm_kernel<<<MTILES * NTILES, 256, 0, stream>>>(Ybf, Wb, b_out, out);
}

// Round 3
// 638.959 us; speedup vs baseline: 1.2700x; 1.2700x over previous
//
#include <hip/hip_runtime.h>

#define VOCAB 10000
#define HIDDEN 256
#define BATCH 32
#define SEQ 256
#define M_ROWS 8192           // SEQ * BATCH
#define NPAD 10112            // 79 * 128
#define NTILES 79
#define MTILES 64             // 8192 / 128
#define LOGITS_ELEMS 81920000LL

typedef __attribute__((ext_vector_type(8))) short short8;
typedef __attribute__((ext_vector_type(4))) float f32x4;

static __device__ __forceinline__ unsigned short f32_to_bf16(float f) {
    unsigned u = __float_as_uint(f);
    u += 0x7fffu + ((u >> 16) & 1u);   // round-to-nearest-even
    return (unsigned short)(u >> 16);
}

// ---------------------------------------------------------------------------
// Kernel 1: W_ihT[v][h] = W_ih[h][v] via 64x64 LDS tile, coalesced both ways.
// grid = 157 v-tiles * 4 h-tiles
// ---------------------------------------------------------------------------
__global__ __launch_bounds__(256) void transpose_wih(const float* __restrict__ W_ih,
                                                     float* __restrict__ W_ihT) {
    __shared__ float tile[64][65];          // +1 pad: conflict-free transpose read
    const int v0   = (blockIdx.x >> 2) * 64;
    const int h0   = (blockIdx.x & 3) * 64;
    const int lane = threadIdx.x & 63;
    const int wv   = threadIdx.x >> 6;      // 0..3

#pragma unroll
    for (int i = 0; i < 16; ++i) {
        const int row = i * 4 + wv;         // h offset within tile
        const int v   = v0 + lane;
        if (v < VOCAB)
            tile[row][lane] = W_ih[(long)(h0 + row) * VOCAB + v];
    }
    __syncthreads();
#pragma unroll
    for (int i = 0; i < 16; ++i) {
        const int vrow = i * 4 + wv;        // v offset within tile
        const int v    = v0 + vrow;
        if (v < VOCAB)
            W_ihT[(long)v * HIDDEN + h0 + lane] = tile[lane][vrow];
    }
}

// ---------------------------------------------------------------------------
// Kernel 2: Wb = bf16(W_out) padded with zero rows to NPAD — one block per row
// ---------------------------------------------------------------------------
__global__ __launch_bounds__(256) void prep_wout(const float* __restrict__ W_out,
                                                 unsigned short* __restrict__ Wb) {
    const int n = blockIdx.x;        // 0..10111
    const int k = threadIdx.x;
    float v = (n < VOCAB) ? W_out[(long)n * HIDDEN + k] : 0.f;
    Wb[(long)n * HIDDEN + k] = f32_to_bf16(v);
}

// ---------------------------------------------------------------------------
// Kernel 3: RNN scan. One block (512 thr, 8 waves) per batch row.
// Thread t: jj=t&63, q=(t>>6)&3 (k-chunk of 64), h2=t>>8.
// Holds W_hh rows {jj+64*(2*h2), jj+64*(2*h2+1)} x cols [64q,64q+64) in VGPRs:
// 128 floats/thread — fits the 256-VGPR cap of __launch_bounds__(512,2),
// unlike the 256-float/thread variant which spilled (VGPR_Count=144,
// FETCH_SIZE=5 GB/dispatch in round 2).
// ---------------------------------------------------------------------------
__global__ __launch_bounds__(512, 2) void scan_kernel(
        const int*   __restrict__ inputs,   // (32, 256)
        const float* __restrict__ state,    // (1, 32, 256)
        const float* __restrict__ W_hh,     // (256, 256)
        const float* __restrict__ b_ih,
        const float* __restrict__ b_hh,
        const float* __restrict__ W_ihT,    // (10000, 256)
        unsigned short* __restrict__ Ybf,   // (8192, 256) bf16
        float* __restrict__ hout)           // (32, 256)
{
    __shared__ float hbuf[HIDDEN];
    __shared__ float psum[4 * HIDDEN];

    const int b  = blockIdx.x;
    const int t  = threadIdx.x;
    const int jj = t & 63;
    const int q  = (t >> 6) & 3;
    const int h2 = t >> 8;

    float w[2][64];
#pragma unroll
    for (int r = 0; r < 2; ++r) {
        const float* src = W_hh + (jj + 64 * (2 * h2 + r)) * HIDDEN + 64 * q;
#pragma unroll
        for (int k4 = 0; k4 < 16; ++k4) {
            const float4 v = *(const float4*)(src + 4 * k4);
            w[r][4 * k4 + 0] = v.x;
            w[r][4 * k4 + 1] = v.y;
            w[r][4 * k4 + 2] = v.z;
            w[r][4 * k4 + 3] = v.w;
        }
    }

    float biasv = 0.f, xcur = 0.f;
    if (t < HIDDEN) {
        biasv   = b_ih[t] + b_hh[t];
        hbuf[t] = state[b * HIDDEN + t];
        const int tok0 = inputs[b * SEQ];
        xcur = W_ihT[(long)tok0 * HIDDEN + t];
    }
    __syncthreads();

    for (int step = 0; step < SEQ; ++step) {
        float xnext = 0.f;
        if (t < HIDDEN && step + 1 < SEQ) {
            const int tokn = inputs[b * SEQ + step + 1];
            xnext = W_ihT[(long)tokn * HIDDEN + t];
        }

        // 4 independent FMA chains: 2 rows x 2 k-halves
        float a00 = 0.f, a01 = 0.f, a10 = 0.f, a11 = 0.f;
#pragma unroll
        for (int k4 = 0; k4 < 8; ++k4) {
            const float4 hv = *(const float4*)&hbuf[64 * q + 4 * k4];  // broadcast
            a00 = fmaf(w[0][4 * k4 + 0], hv.x, a00);
            a00 = fmaf(w[0][4 * k4 + 1], hv.y, a00);
            a00 = fmaf(w[0][4 * k4 + 2], hv.z, a00);
            a00 = fmaf(w[0][4 * k4 + 3], hv.w, a00);
            a10 = fmaf(w[1][4 * k4 + 0], hv.x, a10);
            a10 = fmaf(w[1][4 * k4 + 1], hv.y, a10);
            a10 = fmaf(w[1][4 * k4 + 2], hv.z, a10);
            a10 = fmaf(w[1][4 * k4 + 3], hv.w, a10);
        }
#pragma unroll
        for (int k4 = 8; k4 < 16; ++k4) {
            const float4 hv = *(const float4*)&hbuf[64 * q + 4 * k4];
            a01 = fmaf(w[0][4 * k4 + 0], hv.x, a01);
            a01 = fmaf(w[0][4 * k4 + 1], hv.y, a01);
            a01 = fmaf(w[0][4 * k4 + 2], hv.z, a01);
            a01 = fmaf(w[0][4 * k4 + 3], hv.w, a01);
            a11 = fmaf(w[1][4 * k4 + 0], hv.x, a11);
            a11 = fmaf(w[1][4 * k4 + 1], hv.y, a11);
            a11 = fmaf(w[1][4 * k4 + 2], hv.z, a11);
            a11 = fmaf(w[1][4 * k4 + 3], hv.w, a11);
        }
        psum[q * HIDDEN + jj + 64 * (2 * h2 + 0)] = a00 + a01;  // stride-1 per wave
        psum[q * HIDDEN + jj + 64 * (2 * h2 + 1)] = a10 + a11;
        __syncthreads();

        if (t < HIDDEN) {   // wave-uniform branch (waves 0-3)
            const float s = psum[t] + psum[HIDDEN + t]
                          + psum[2 * HIDDEN + t] + psum[3 * HIDDEN + t];
            const float hnew = tanhf(s + xcur + biasv);
            hbuf[t] = hnew;
            Ybf[((long)step * BATCH + b) * HIDDEN + t] = f32_to_bf16(hnew);
            xcur = xnext;
        }
        __syncthreads();
    }

    if (t < HIDDEN) hout[b * HIDDEN + t] = hbuf[t];
}

// ---------------------------------------------------------------------------
// Kernel 4: logits = Y(bf16) @ Wb^T + b_out.  m97-style 128x128 tile, BK=64,
// global_load_lds width-16 staging, 16x16x32 bf16 MFMA, 4x4 frags per wave.
// ---------------------------------------------------------------------------
__global__ __launch_bounds__(256) void gemm_kernel(
        const unsigned short* __restrict__ A,   // (8192, 256) bf16
        const unsigned short* __restrict__ B,   // (10112, 256) bf16
        const float* __restrict__ bias,         // (10000,)
        float* __restrict__ C)                  // (8192, 10000) f32
{
    __shared__ unsigned short lA[128 * 64];
    __shared__ unsigned short lB[128 * 64];

    const int t     = threadIdx.x;
    const int bid   = blockIdx.x;
    const int ntile = bid % NTILES;
    const int mtile = bid / NTILES;
    const long m0   = (long)mtile * 128;
    const long n0   = (long)ntile * 128;
    const int lane  = t & 63;
    const int wave  = t >> 6;
    const int wm    = (wave & 1) * 64;
    const int wn    = (wave >> 1) * 64;
    const int l15   = lane & 15;
    const int quad  = lane >> 4;

    const f32x4 zero = {0.f, 0.f, 0.f, 0.f};
    f32x4 acc[4][4];
#pragma unroll
    for (int i = 0; i < 4; ++i)
#pragma unroll
        for (int j = 0; j < 4; ++j)
            acc[i][j] = zero;

    for (int kb = 0; kb < 4; ++kb) {
        if (kb) __syncthreads();
#pragma unroll
        for (int it = 0; it < 4; ++it) {
            const int c   = it * 256 + t;
            const int row = c >> 3;
            const int k8  = c & 7;
            const unsigned short* ga = A + (m0 + row) * HIDDEN + kb * 64 + k8 * 8;
            const unsigned short* gb = B + (n0 + row) * HIDDEN + kb * 64 + k8 * 8;
            __builtin_amdgcn_global_load_lds(
                (const __attribute__((address_space(1))) void*)ga,
                (__attribute__((address_space(3))) void*)(lA + c * 8), 16, 0, 0);
            __builtin_amdgcn_global_load_lds(
                (const __attribute__((address_space(1))) void*)gb,
                (__attribute__((address_space(3))) void*)(lB + c * 8), 16, 0, 0);
        }
        __syncthreads();

#pragma unroll
        for (int ki = 0; ki < 2; ++ki) {
            short8 af[4], bf[4];
#pragma unroll
            for (int i = 0; i < 4; ++i) {
                af[i] = *(const short8*)&lA[(wm + 16 * i + l15) * 64 + ki * 32 + quad * 8];
                bf[i] = *(const short8*)&lB[(wn + 16 * i + l15) * 64 + ki * 32 + quad * 8];
            }
#pragma unroll
            for (int i = 0; i < 4; ++i)
#pragma unroll
                for (int j = 0; j < 4; ++j)
                    acc[i][j] = __builtin_amdgcn_mfma_f32_16x16x32_bf16(
                        af[i], bf[j], acc[i][j], 0, 0, 0);
        }
    }

    // epilogue: C/D layout col = lane&15, row = quad*4 + reg
#pragma unroll
    for (int j = 0; j < 4; ++j) {
        const long col = n0 + wn + 16 * j + l15;
        if (col < VOCAB) {
            const float bv = bias[col];
#pragma unroll
            for (int i = 0; i < 4; ++i) {
                const long row = m0 + wm + 16 * i + quad * 4;
                float* Cp = C + row * VOCAB + col;
#pragma unroll
                for (int r = 0; r < 4; ++r)
                    Cp[(long)r * VOCAB] = acc[i][j][r] + bv;
            }
        }
    }
}

// ---------------------------------------------------------------------------
extern "C" void kernel_launch(void* const* d_in, const int* in_sizes, int n_in,
                              void* d_out, int out_size, void* d_ws, size_t ws_size,
                              hipStream_t stream) {
    const int*   inputs = (const int*)  d_in[0];
    const float* state  = (const float*)d_in[1];
    const float* W_ih   = (const float*)d_in[2];
    const float* b_ih   = (const float*)d_in[3];
    const float* W_hh   = (const float*)d_in[4];
    const float* b_hh   = (const float*)d_in[5];
    const float* W_out  = (const float*)d_in[6];
    const float* b_out  = (const float*)d_in[7];
    float* out = (float*)d_out;

    char* ws = (char*)d_ws;
    float*          W_ihT = (float*)ws;                        // 10,240,000 B
    unsigned short* Wb    = (unsigned short*)(ws + 10240000);  //  5,177,344 B
    unsigned short* Ybf   = (unsigned short*)(ws + 15417344);  //  4,194,304 B

    transpose_wih<<<157 * 4, 256, 0, stream>>>(W_ih, W_ihT);
    prep_wout<<<NPAD, 256, 0, stream>>>(W_out, Wb);
    scan_kernel<<<BATCH, 512, 0, stream>>>(inputs, state, W_hh, b_ih, b_hh,
                                           W_ihT, Ybf, out + LOGITS_ELEMS);
    gemm_kernel<<<MTILES * NTILES, 256, 0, stream>>>(Ybf, Wb, b_out, out);
}